// Round 10
// baseline (284.543 us; speedup 1.0000x reference)
//
#include <hip/hip_runtime.h>
#include <math.h>

#define BB 8
#define NN 512
#define DD 1024
#define HH 16
#define DH 64
#define INNER 1024
#define QKV3 3072

typedef __attribute__((ext_vector_type(8))) short short8;
typedef __attribute__((ext_vector_type(4))) float f32x4;

#define AS1 __attribute__((address_space(1)))
#define AS3 __attribute__((address_space(3)))

__device__ __forceinline__ float4 ld4(const float* p) { return *(const float4*)p; }

__device__ __forceinline__ unsigned short f2bf(float f) {
    unsigned u = __float_as_uint(f);
    return (unsigned short)((u + 0x7fffu + ((u >> 16) & 1u)) >> 16);
}
__device__ __forceinline__ float bf2f(unsigned short u) {
    return __uint_as_float(((unsigned)u) << 16);
}

// ---------------------------------------------------------------------------
// fp32 -> bf16 elementwise convert (4 els/thread)
// ---------------------------------------------------------------------------
__global__ void conv_bf16(const float* __restrict__ in, unsigned short* __restrict__ out) {
    size_t i = ((size_t)blockIdx.x * 256 + threadIdx.x) * 4;
    float4 v = ld4(in + i);
    ushort4 o;
    o.x = f2bf(v.x); o.y = f2bf(v.y); o.z = f2bf(v.z); o.w = f2bf(v.w);
    *(ushort4*)(out + i) = o;
}

// ---------------------------------------------------------------------------
// sum two bf16 partial buffers -> bf16 (4 els/thread)
// ---------------------------------------------------------------------------
__global__ void sum_po(const unsigned short* __restrict__ a,
                       const unsigned short* __restrict__ b,
                       unsigned short* __restrict__ o) {
    size_t i = ((size_t)blockIdx.x * 256 + threadIdx.x) * 4;
    ushort4 ua = *(const ushort4*)(a + i);
    ushort4 ub = *(const ushort4*)(b + i);
    ushort4 uo;
    uo.x = f2bf(bf2f(ua.x) + bf2f(ub.x));
    uo.y = f2bf(bf2f(ua.y) + bf2f(ub.y));
    uo.z = f2bf(bf2f(ua.z) + bf2f(ub.z));
    uo.w = f2bf(bf2f(ua.w) + bf2f(ub.w));
    *(ushort4*)(o + i) = uo;
}

// ---------------------------------------------------------------------------
// fp32 [K][N] -> bf16 [N][K] transpose-convert, 32x32 LDS tiles
// ---------------------------------------------------------------------------
__global__ void convT_bf16(const float* __restrict__ in, unsigned short* __restrict__ out,
                           int K, int N) {
    __shared__ float t[32][33];
    const int n0 = blockIdx.x * 32, k0 = blockIdx.y * 32;
    const int tx = threadIdx.x & 31, ty = threadIdx.x >> 5;  // 32 x 8
#pragma unroll
    for (int l = 0; l < 4; ++l)
        t[ty + 8 * l][tx] = in[(size_t)(k0 + ty + 8 * l) * N + n0 + tx];
    __syncthreads();
#pragma unroll
    for (int l = 0; l < 4; ++l)
        out[(size_t)(n0 + ty + 8 * l) * K + k0 + tx] = f2bf(t[tx][ty + 8 * l]);
}

// ---------------------------------------------------------------------------
// bf16 MFMA GEMM, fp32 out (+bias): C[M,N] = A[M,K] * Bt[N,K]^T
// ---------------------------------------------------------------------------
__global__ __launch_bounds__(256) void gemm_bf16(
    const unsigned short* __restrict__ A, const unsigned short* __restrict__ Bt,
    float* __restrict__ C, const float* __restrict__ bias, int M, int N, int K) {
    __shared__ short As[128 * 32];
    __shared__ short Bs[128 * 32];
    const int tid = threadIdx.x;
    const int w = tid >> 6, l = tid & 63;
    const int bm = blockIdx.y * 128, bn = blockIdx.x * 128;
    const int wm = (w >> 1) * 64, wn = (w & 1) * 64;
    const int lrow = l & 15, lq = l >> 4;

    f32x4 acc[4][4];
#pragma unroll
    for (int i = 0; i < 4; ++i)
#pragma unroll
        for (int j = 0; j < 4; ++j) acc[i][j] = (f32x4){0.f, 0.f, 0.f, 0.f};

    for (int k0 = 0; k0 < K; k0 += 32) {
#pragma unroll
        for (int t = 0; t < 2; ++t) {
            const int q = w * 2 + t;
            const int li = q * 512 + l * 8;
            const int row = li >> 5, kc = li & 31;
            const unsigned short* ga = A + (size_t)(bm + row) * K + k0 + kc;
            __builtin_amdgcn_global_load_lds(
                (const AS1 void*)ga, (AS3 void*)(As + q * 512), 16, 0, 0);
            const unsigned short* gb = Bt + (size_t)(bn + row) * K + k0 + kc;
            __builtin_amdgcn_global_load_lds(
                (const AS1 void*)gb, (AS3 void*)(Bs + q * 512), 16, 0, 0);
        }
        __syncthreads();

        short8 a[4], b[4];
#pragma unroll
        for (int i = 0; i < 4; ++i)
            a[i] = *(const short8*)(As + (wm + i * 16 + lrow) * 32 + lq * 8);
#pragma unroll
        for (int j = 0; j < 4; ++j)
            b[j] = *(const short8*)(Bs + (wn + j * 16 + lrow) * 32 + lq * 8);
#pragma unroll
        for (int i = 0; i < 4; ++i)
#pragma unroll
            for (int j = 0; j < 4; ++j)
                acc[i][j] = __builtin_amdgcn_mfma_f32_16x16x32_bf16(a[i], b[j], acc[i][j], 0, 0, 0);
        __syncthreads();
    }

#pragma unroll
    for (int i = 0; i < 4; ++i)
#pragma unroll
        for (int j = 0; j < 4; ++j) {
            const int col = bn + wn + j * 16 + lrow;
            const float bv = bias ? bias[col] : 0.f;
#pragma unroll
            for (int r = 0; r < 4; ++r) {
                const int row = bm + wm + i * 16 + lq * 4 + r;
                C[(size_t)row * N + col] = acc[i][j][r] + bv;
            }
        }
}

// ---------------------------------------------------------------------------
// Same GEMM but bf16 output, no bias (QKV projection)
// ---------------------------------------------------------------------------
__global__ __launch_bounds__(256) void gemm_bf16_bf(
    const unsigned short* __restrict__ A, const unsigned short* __restrict__ Bt,
    unsigned short* __restrict__ C, int M, int N, int K) {
    __shared__ short As[128 * 32];
    __shared__ short Bs[128 * 32];
    const int tid = threadIdx.x;
    const int w = tid >> 6, l = tid & 63;
    const int bm = blockIdx.y * 128, bn = blockIdx.x * 128;
    const int wm = (w >> 1) * 64, wn = (w & 1) * 64;
    const int lrow = l & 15, lq = l >> 4;

    f32x4 acc[4][4];
#pragma unroll
    for (int i = 0; i < 4; ++i)
#pragma unroll
        for (int j = 0; j < 4; ++j) acc[i][j] = (f32x4){0.f, 0.f, 0.f, 0.f};

    for (int k0 = 0; k0 < K; k0 += 32) {
#pragma unroll
        for (int t = 0; t < 2; ++t) {
            const int q = w * 2 + t;
            const int li = q * 512 + l * 8;
            const int row = li >> 5, kc = li & 31;
            const unsigned short* ga = A + (size_t)(bm + row) * K + k0 + kc;
            __builtin_amdgcn_global_load_lds(
                (const AS1 void*)ga, (AS3 void*)(As + q * 512), 16, 0, 0);
            const unsigned short* gb = Bt + (size_t)(bn + row) * K + k0 + kc;
            __builtin_amdgcn_global_load_lds(
                (const AS1 void*)gb, (AS3 void*)(Bs + q * 512), 16, 0, 0);
        }
        __syncthreads();

        short8 a[4], b[4];
#pragma unroll
        for (int i = 0; i < 4; ++i)
            a[i] = *(const short8*)(As + (wm + i * 16 + lrow) * 32 + lq * 8);
#pragma unroll
        for (int j = 0; j < 4; ++j)
            b[j] = *(const short8*)(Bs + (wn + j * 16 + lrow) * 32 + lq * 8);
#pragma unroll
        for (int i = 0; i < 4; ++i)
#pragma unroll
            for (int j = 0; j < 4; ++j)
                acc[i][j] = __builtin_amdgcn_mfma_f32_16x16x32_bf16(a[i], b[j], acc[i][j], 0, 0, 0);
        __syncthreads();
    }

#pragma unroll
    for (int i = 0; i < 4; ++i)
#pragma unroll
        for (int j = 0; j < 4; ++j) {
            const int col = bn + wn + j * 16 + lrow;
#pragma unroll
            for (int r = 0; r < 4; ++r) {
                const int row = bm + wm + i * 16 + lq * 4 + r;
                C[(size_t)row * N + col] = f2bf(acc[i][j][r]);
            }
        }
}

// ---------------------------------------------------------------------------
// STREAMING scores (R7, unchanged): j-split x2, 4-deep register prefetch,
// no max-sub (scores bounded). attn gets UNNORMALIZED exp; partial row-sums
// -> lsum2[jh][bh][i]; reattn_pv folds 1/(l0+l1) into its load.
// ---------------------------------------------------------------------------
__global__ __launch_bounds__(256) void scores_stream(
    const unsigned short* __restrict__ qkvb, unsigned short* __restrict__ attnb,
    float* __restrict__ lsum2) {
    const int bh = blockIdx.z;
    const int h = bh & 15, b = bh >> 4;
    const int jh = blockIdx.y;                 // j half: 0 or 1
    const int w = threadIdx.x >> 6, l = threadIdx.x & 63;
    const int i0 = blockIdx.x * 64 + w * 16;   // wave-private 16-row i-tile
    const int lrow = l & 15, lq = l >> 4;

    const unsigned short* qb = qkvb + (size_t)(b * NN) * QKV3 + h * DH + lq * 8;
    const unsigned short* kb = qkvb + (size_t)(b * NN) * QKV3 + INNER + h * DH + lq * 8;

    const short8 qf0 = *(const short8*)(qb + (size_t)(i0 + lrow) * QKV3);
    const short8 qf1 = *(const short8*)(qb + (size_t)(i0 + lrow) * QKV3 + 32);

    const unsigned short* krow = kb + (size_t)(jh * 256 + lrow) * QKV3;
    unsigned short* orow = attnb + ((size_t)bh * NN + i0 + lrow) * NN + jh * 256 + lq * 4;

    short8 ka[4], kc[4];
#pragma unroll
    for (int p = 0; p < 4; ++p) {
        const unsigned short* kp = krow + (size_t)p * 16 * QKV3;
        ka[p] = *(const short8*)(kp);
        kc[p] = *(const short8*)(kp + 32);
    }

    float lacc = 0.f;
#pragma unroll
    for (int jt = 0; jt < 16; ++jt) {
        const int s = jt & 3;
        short8 kf0 = ka[s], kf1 = kc[s];
        if (jt < 12) {
            const unsigned short* kp = krow + (size_t)(jt + 4) * 16 * QKV3;
            ka[s] = *(const short8*)(kp);
            kc[s] = *(const short8*)(kp + 32);
        }
        f32x4 acc = (f32x4){0.f, 0.f, 0.f, 0.f};
        acc = __builtin_amdgcn_mfma_f32_16x16x32_bf16(kf0, qf0, acc, 0, 0, 0);
        acc = __builtin_amdgcn_mfma_f32_16x16x32_bf16(kf1, qf1, acc, 0, 0, 0);
        float e0 = __expf(acc[0] * 0.125f);
        float e1 = __expf(acc[1] * 0.125f);
        float e2 = __expf(acc[2] * 0.125f);
        float e3 = __expf(acc[3] * 0.125f);
        lacc += (e0 + e1) + (e2 + e3);
        ushort4 o;
        o.x = f2bf(e0); o.y = f2bf(e1); o.z = f2bf(e2); o.w = f2bf(e3);
        *(ushort4*)(orow + jt * 16) = o;
    }
    lacc += __shfl_xor(lacc, 16, 64);
    lacc += __shfl_xor(lacc, 32, 64);
    if (lq == 0)
        lsum2[(size_t)jh * BB * HH * NN + (size_t)bh * NN + i0 + lrow] = lacc;
}

// ---------------------------------------------------------------------------
// V transpose: qkvb [b,j,2048+h*64+d] -> vT [bh, d, j] (bf16)
// ---------------------------------------------------------------------------
__global__ void transpose_v(const unsigned short* __restrict__ qkvb,
                            unsigned short* __restrict__ vT) {
    __shared__ unsigned short t[32][33];
    const int bh = blockIdx.z;
    const int h = bh & 15, b = bh >> 4;
    const int j0 = blockIdx.x * 32, d0 = blockIdx.y * 32;
    const int tx = threadIdx.x & 31, ty = threadIdx.x >> 5;
    const unsigned short* src = qkvb + (size_t)(b * NN) * QKV3 + 2 * INNER + h * DH;
#pragma unroll
    for (int k = 0; k < 4; ++k)
        t[ty + 8 * k][tx] = src[(size_t)(j0 + ty + 8 * k) * QKV3 + d0 + tx];
    __syncthreads();
    unsigned short* dst = vT + (size_t)bh * DH * NN;
#pragma unroll
    for (int k = 0; k < 4; ++k)
        dst[(size_t)(d0 + ty + 8 * k) * NN + j0 + tx] = t[tx][ty + 8 * k];
}

// ---------------------------------------------------------------------------
// FUSED re-attention + LN + PV, j-split x2 for 2 blocks/CU co-residency
// (R9's 1 block/CU serialized the stage/mix/PV phases -- 87us with all pipes
// idle). Block = (b, 16 i-rows, j-half); 1024 threads = 16 waves, wave = head.
// Per 128-j chunk (2 per block):
//   (a) stage P[16h][16i][128j] bf16 (64 KB) via global_load_lds, XOR-swizzled
//   (b) head-mix + LN in place (thread owns (i,j) across all 16 heads)
//   (c) per-head PV MFMA, partial O over this block's 256 j's
// Partial O -> po[jh] bf16; sum_po adds the halves.
// ---------------------------------------------------------------------------
__global__ __launch_bounds__(1024) void reattn_pv(
    const unsigned short* __restrict__ attnb, const float* __restrict__ lsum2,
    const unsigned short* __restrict__ vT, unsigned short* __restrict__ po,
    const float* __restrict__ rw, const float* __restrict__ gamma,
    const float* __restrict__ beta) {
    __shared__ unsigned short P[16 * 2048];   // [h][16i x 128j], 64 KB
    __shared__ float wmix[16][16];
    __shared__ float gsb[2][16];
    __shared__ float linv_s[16][16];          // [h][i]

    const int b = blockIdx.z;
    const int jh = blockIdx.y;                // j half: 0 or 1
    const int i0 = blockIdx.x * 16;
    const int tid = threadIdx.x;
    const int h = tid >> 6;                   // wave = head
    const int l = tid & 63;
    const int lrow = l & 15, lq = l >> 4;

    if (tid < 256) ((float*)wmix)[tid] = rw[tid];
    if (tid < 16) { gsb[0][tid] = gamma[tid]; gsb[1][tid] = beta[tid]; }
    if (tid < 256) {
        const int hh = tid >> 4, ii = tid & 15;
        const size_t off = (size_t)(b * HH + hh) * NN + i0 + ii;
        linv_s[hh][ii] = 1.0f / (lsum2[off] + lsum2[(size_t)BB * HH * NN + off]);
    }

    const unsigned short* pb = attnb + ((size_t)(b * HH + h) * NN + i0) * NN;
    const unsigned short* vb = vT + (size_t)(b * HH + h) * DH * NN;

    const int mi = tid >> 6;                  // mix-phase i row
    const int mj = (tid & 63) * 2;            // mix-phase j pair base
    const int mch = (((mj >> 3) ^ (mi & 7)) * 8) + (mj & 7);

    f32x4 oacc[4];
#pragma unroll
    for (int dt = 0; dt < 4; ++dt) oacc[dt] = (f32x4){0.f, 0.f, 0.f, 0.f};

    for (int jc = 0; jc < 2; ++jc) {
        const int j0 = jh * 256 + jc * 128;
        // (a) stage: wave h loads its head plane, 4 x 1KB instrs
#pragma unroll
        for (int t = 0; t < 4; ++t) {
            const int row = t * 4 + (l >> 4);
            const int sc = (l & 15) ^ (row & 7);
            __builtin_amdgcn_global_load_lds(
                (const AS1 void*)(pb + (size_t)row * NN + j0 + sc * 8),
                (AS3 void*)(P + h * 2048 + t * 512), 16, 0, 0);
        }
        __syncthreads();

        // (b) head-mix + LN in place
        {
            unsigned int u2[16];
#pragma unroll
            for (int hh = 0; hh < 16; ++hh)
                u2[hh] = *(const unsigned int*)&P[hh * 2048 + mi * 128 + mch];
#pragma unroll
            for (int jj = 0; jj < 2; ++jj) {
                float v[16], o[16];
#pragma unroll
                for (int hh = 0; hh < 16; ++hh) {
                    const unsigned short us = jj ? (unsigned short)(u2[hh] >> 16)
                                                 : (unsigned short)(u2[hh] & 0xffffu);
                    v[hh] = bf2f(us) * linv_s[hh][mi];
                }
                float me = 0.f;
#pragma unroll
                for (int g = 0; g < 16; ++g) {
                    float s = 0.f;
#pragma unroll
                    for (int hh = 0; hh < 16; ++hh) s += v[hh] * wmix[hh][g];
                    o[g] = s;
                    me += s;
                }
                me *= 0.0625f;
                float va = 0.f;
#pragma unroll
                for (int g = 0; g < 16; ++g) {
                    const float d = o[g] - me;
                    va += d * d;
                }
                const float ri = rsqrtf(va * 0.0625f + 1e-3f);
#pragma unroll
                for (int g = 0; g < 16; ++g) {
                    const unsigned short r =
                        f2bf((o[g] - me) * ri * gsb[0][g] + gsb[1][g]);
                    u2[g] = jj ? ((u2[g] & 0x0000ffffu) | ((unsigned)r << 16))
                               : ((u2[g] & 0xffff0000u) | (unsigned)r);
                }
            }
#pragma unroll
            for (int hh = 0; hh < 16; ++hh)
                *(unsigned int*)&P[hh * 2048 + mi * 128 + mch] = u2[hh];
        }
        __syncthreads();

        // (c) PV accumulate for this chunk (wave = head h)
#pragma unroll
        for (int jk = 0; jk < 4; ++jk) {
            const short8 pf = *(const short8*)&P[h * 2048 + lrow * 128 +
                                                 (((jk * 4 + lq) ^ (lrow & 7)) * 8)];
#pragma unroll
            for (int dt = 0; dt < 4; ++dt) {
                const short8 vf = *(const short8*)(vb + (size_t)(dt * 16 + lrow) * NN +
                                                   j0 + jk * 32 + lq * 8);
                oacc[dt] = __builtin_amdgcn_mfma_f32_16x16x32_bf16(vf, pf, oacc[dt], 0, 0, 0);
            }
        }
        if (jc == 0) __syncthreads();   // guard P overwrite next chunk
    }

    // epilogue: partial O^T -> po[jh]; lane col=i=lrow, rows d=dt*16+lq*4+r
    unsigned short* orow = po + (size_t)jh * BB * NN * INNER +
                           (size_t)(b * NN + i0 + lrow) * INNER + h * DH + lq * 4;
#pragma unroll
    for (int dt = 0; dt < 4; ++dt) {
        ushort4 o;
        o.x = f2bf(oacc[dt][0]); o.y = f2bf(oacc[dt][1]);
        o.z = f2bf(oacc[dt][2]); o.w = f2bf(oacc[dt][3]);
        *(ushort4*)(orow + dt * 16) = o;
    }
}

// ---------------------------------------------------------------------------
extern "C" void kernel_launch(void* const* d_in, const int* in_sizes, int n_in,
                              void* d_out, int out_size, void* d_ws, size_t ws_size,
                              hipStream_t stream) {
    const float* x        = (const float*)d_in[0];
    const float* w_qkv    = (const float*)d_in[1];
    const float* reattn_w = (const float*)d_in[2];
    const float* ln_gamma = (const float*)d_in[3];
    const float* ln_beta  = (const float*)d_in[4];
    const float* w_out    = (const float*)d_in[5];
    const float* b_out    = (const float*)d_in[6];
    float* out = (float*)d_out;

    unsigned short* qkvb  = (unsigned short*)d_ws;                 // 12.58M
    unsigned short* attnb = qkvb + (size_t)BB * NN * QKV3;         // 33.55M
    unsigned short* vTb   = attnb + (size_t)BB * HH * NN * NN;     // 4.19M
    unsigned short* outhb = vTb + (size_t)BB * HH * DH * NN;       // 4.19M
    unsigned short* xb    = outhb + (size_t)BB * NN * INNER;       // 4.19M
    unsigned short* wqkvT = xb + (size_t)BB * NN * DD;             // 3.15M
    unsigned short* woutT = wqkvT + (size_t)DD * QKV3;             // 1.05M
    float*          lsum2 = (float*)(woutT + (size_t)INNER * INNER);  // 2*B*H*N f32
    unsigned short* po    = (unsigned short*)(lsum2 + 2 * (size_t)BB * HH * NN); // 2*B*N*INNER

    dim3 blk(256);

    conv_bf16<<<dim3((BB * NN * DD) / 1024), blk, 0, stream>>>(x, xb);
    convT_bf16<<<dim3(QKV3 / 32, DD / 32), blk, 0, stream>>>(w_qkv, wqkvT, DD, QKV3);
    convT_bf16<<<dim3(INNER / 32, INNER / 32), blk, 0, stream>>>(w_out, woutT, INNER, INNER);

    // QKV projection -> bf16
    gemm_bf16_bf<<<dim3(QKV3 / 128, (BB * NN) / 128), blk, 0, stream>>>(
        xb, wqkvT, qkvb, BB * NN, QKV3, DD);

    // streaming scores: unnormalized exp -> attn bf16, partial row-sums -> lsum2
    scores_stream<<<dim3(NN / 64, 2, BB * HH), blk, 0, stream>>>(qkvb, attnb, lsum2);

    // V transpose -> [bh][d][j]
    transpose_v<<<dim3(NN / 32, DH / 32, BB * HH), blk, 0, stream>>>(qkvb, vTb);

    // fused re-attention + LN + PV, j-split x2 -> partial O
    reattn_pv<<<dim3(NN / 16, 2, BB), dim3(1024), 0, stream>>>(
        attnb, lsum2, vTb, po, reattn_w, ln_gamma, ln_beta);

    // sum partial O halves -> outh bf16
    sum_po<<<dim3((BB * NN * INNER) / 1024), blk, 0, stream>>>(
        po, po + (size_t)BB * NN * INNER, outhb);

    // output projection + bias (fp32 out)
    gemm_bf16<<<dim3(INNER / 128, (BB * NN) / 128), blk, 0, stream>>>(
        outhb, woutT, out, b_out, BB * NN, INNER, INNER);
}

// Round 11
// 245.703 us; speedup vs baseline: 1.1581x; 1.1581x over previous
//
#include <hip/hip_runtime.h>
#include <math.h>

#define BB 8
#define NN 512
#define DD 1024
#define HH 16
#define DH 64
#define INNER 1024
#define QKV3 3072
// attn head-plane stride in shorts: N*N + 64 (128B pad) breaks the exact
// 512KB power-of-2 stride that aliases all 16 head planes onto the same
// L2-set/HBM-channel group in reattn_ln_bf's 16-plane gather.
#define PSTR (NN * NN + 64)

typedef __attribute__((ext_vector_type(8))) short short8;
typedef __attribute__((ext_vector_type(4))) float f32x4;

#define AS1 __attribute__((address_space(1)))
#define AS3 __attribute__((address_space(3)))

__device__ __forceinline__ float4 ld4(const float* p) { return *(const float4*)p; }

__device__ __forceinline__ unsigned short f2bf(float f) {
    unsigned u = __float_as_uint(f);
    return (unsigned short)((u + 0x7fffu + ((u >> 16) & 1u)) >> 16);
}
__device__ __forceinline__ float bf2f(unsigned short u) {
    return __uint_as_float(((unsigned)u) << 16);
}

// ---------------------------------------------------------------------------
// fp32 -> bf16 elementwise convert (4 els/thread)
// ---------------------------------------------------------------------------
__global__ void conv_bf16(const float* __restrict__ in, unsigned short* __restrict__ out) {
    size_t i = ((size_t)blockIdx.x * 256 + threadIdx.x) * 4;
    float4 v = ld4(in + i);
    ushort4 o;
    o.x = f2bf(v.x); o.y = f2bf(v.y); o.z = f2bf(v.z); o.w = f2bf(v.w);
    *(ushort4*)(out + i) = o;
}

// ---------------------------------------------------------------------------
// fp32 [K][N] -> bf16 [N][K] transpose-convert, 32x32 LDS tiles
// ---------------------------------------------------------------------------
__global__ void convT_bf16(const float* __restrict__ in, unsigned short* __restrict__ out,
                           int K, int N) {
    __shared__ float t[32][33];
    const int n0 = blockIdx.x * 32, k0 = blockIdx.y * 32;
    const int tx = threadIdx.x & 31, ty = threadIdx.x >> 5;  // 32 x 8
#pragma unroll
    for (int l = 0; l < 4; ++l)
        t[ty + 8 * l][tx] = in[(size_t)(k0 + ty + 8 * l) * N + n0 + tx];
    __syncthreads();
#pragma unroll
    for (int l = 0; l < 4; ++l)
        out[(size_t)(n0 + ty + 8 * l) * K + k0 + tx] = f2bf(t[tx][ty + 8 * l]);
}

// ---------------------------------------------------------------------------
// bf16 MFMA GEMM, fp32 out (+bias): C[M,N] = A[M,K] * Bt[N,K]^T
// ---------------------------------------------------------------------------
__global__ __launch_bounds__(256) void gemm_bf16(
    const unsigned short* __restrict__ A, const unsigned short* __restrict__ Bt,
    float* __restrict__ C, const float* __restrict__ bias, int M, int N, int K) {
    __shared__ short As[128 * 32];
    __shared__ short Bs[128 * 32];
    const int tid = threadIdx.x;
    const int w = tid >> 6, l = tid & 63;
    const int bm = blockIdx.y * 128, bn = blockIdx.x * 128;
    const int wm = (w >> 1) * 64, wn = (w & 1) * 64;
    const int lrow = l & 15, lq = l >> 4;

    f32x4 acc[4][4];
#pragma unroll
    for (int i = 0; i < 4; ++i)
#pragma unroll
        for (int j = 0; j < 4; ++j) acc[i][j] = (f32x4){0.f, 0.f, 0.f, 0.f};

    for (int k0 = 0; k0 < K; k0 += 32) {
#pragma unroll
        for (int t = 0; t < 2; ++t) {
            const int q = w * 2 + t;
            const int li = q * 512 + l * 8;
            const int row = li >> 5, kc = li & 31;
            const unsigned short* ga = A + (size_t)(bm + row) * K + k0 + kc;
            __builtin_amdgcn_global_load_lds(
                (const AS1 void*)ga, (AS3 void*)(As + q * 512), 16, 0, 0);
            const unsigned short* gb = Bt + (size_t)(bn + row) * K + k0 + kc;
            __builtin_amdgcn_global_load_lds(
                (const AS1 void*)gb, (AS3 void*)(Bs + q * 512), 16, 0, 0);
        }
        __syncthreads();

        short8 a[4], b[4];
#pragma unroll
        for (int i = 0; i < 4; ++i)
            a[i] = *(const short8*)(As + (wm + i * 16 + lrow) * 32 + lq * 8);
#pragma unroll
        for (int j = 0; j < 4; ++j)
            b[j] = *(const short8*)(Bs + (wn + j * 16 + lrow) * 32 + lq * 8);
#pragma unroll
        for (int i = 0; i < 4; ++i)
#pragma unroll
            for (int j = 0; j < 4; ++j)
                acc[i][j] = __builtin_amdgcn_mfma_f32_16x16x32_bf16(a[i], b[j], acc[i][j], 0, 0, 0);
        __syncthreads();
    }

#pragma unroll
    for (int i = 0; i < 4; ++i)
#pragma unroll
        for (int j = 0; j < 4; ++j) {
            const int col = bn + wn + j * 16 + lrow;
            const float bv = bias ? bias[col] : 0.f;
#pragma unroll
            for (int r = 0; r < 4; ++r) {
                const int row = bm + wm + i * 16 + lq * 4 + r;
                C[(size_t)row * N + col] = acc[i][j][r] + bv;
            }
        }
}

// ---------------------------------------------------------------------------
// Same GEMM but bf16 output, no bias (QKV projection)
// ---------------------------------------------------------------------------
__global__ __launch_bounds__(256) void gemm_bf16_bf(
    const unsigned short* __restrict__ A, const unsigned short* __restrict__ Bt,
    unsigned short* __restrict__ C, int M, int N, int K) {
    __shared__ short As[128 * 32];
    __shared__ short Bs[128 * 32];
    const int tid = threadIdx.x;
    const int w = tid >> 6, l = tid & 63;
    const int bm = blockIdx.y * 128, bn = blockIdx.x * 128;
    const int wm = (w >> 1) * 64, wn = (w & 1) * 64;
    const int lrow = l & 15, lq = l >> 4;

    f32x4 acc[4][4];
#pragma unroll
    for (int i = 0; i < 4; ++i)
#pragma unroll
        for (int j = 0; j < 4; ++j) acc[i][j] = (f32x4){0.f, 0.f, 0.f, 0.f};

    for (int k0 = 0; k0 < K; k0 += 32) {
#pragma unroll
        for (int t = 0; t < 2; ++t) {
            const int q = w * 2 + t;
            const int li = q * 512 + l * 8;
            const int row = li >> 5, kc = li & 31;
            const unsigned short* ga = A + (size_t)(bm + row) * K + k0 + kc;
            __builtin_amdgcn_global_load_lds(
                (const AS1 void*)ga, (AS3 void*)(As + q * 512), 16, 0, 0);
            const unsigned short* gb = Bt + (size_t)(bn + row) * K + k0 + kc;
            __builtin_amdgcn_global_load_lds(
                (const AS1 void*)gb, (AS3 void*)(Bs + q * 512), 16, 0, 0);
        }
        __syncthreads();

        short8 a[4], b[4];
#pragma unroll
        for (int i = 0; i < 4; ++i)
            a[i] = *(const short8*)(As + (wm + i * 16 + lrow) * 32 + lq * 8);
#pragma unroll
        for (int j = 0; j < 4; ++j)
            b[j] = *(const short8*)(Bs + (wn + j * 16 + lrow) * 32 + lq * 8);
#pragma unroll
        for (int i = 0; i < 4; ++i)
#pragma unroll
            for (int j = 0; j < 4; ++j)
                acc[i][j] = __builtin_amdgcn_mfma_f32_16x16x32_bf16(a[i], b[j], acc[i][j], 0, 0, 0);
        __syncthreads();
    }

#pragma unroll
    for (int i = 0; i < 4; ++i)
#pragma unroll
        for (int j = 0; j < 4; ++j) {
            const int col = bn + wn + j * 16 + lrow;
#pragma unroll
            for (int r = 0; r < 4; ++r) {
                const int row = bm + wm + i * 16 + lq * 4 + r;
                C[(size_t)row * N + col] = f2bf(acc[i][j][r]);
            }
        }
}

// ---------------------------------------------------------------------------
// STREAMING scores (R7): j-split x2, 4-deep register prefetch, no max-sub
// (scores bounded, fp32 exp can't overflow). attn gets UNNORMALIZED exp with
// PADDED plane stride; partial row-sums -> lsum2[jh][bh][i].
// ---------------------------------------------------------------------------
__global__ __launch_bounds__(256) void scores_stream(
    const unsigned short* __restrict__ qkvb, unsigned short* __restrict__ attnb,
    float* __restrict__ lsum2) {
    const int bh = blockIdx.z;
    const int h = bh & 15, b = bh >> 4;
    const int jh = blockIdx.y;                 // j half: 0 or 1
    const int w = threadIdx.x >> 6, l = threadIdx.x & 63;
    const int i0 = blockIdx.x * 64 + w * 16;   // wave-private 16-row i-tile
    const int lrow = l & 15, lq = l >> 4;

    const unsigned short* qb = qkvb + (size_t)(b * NN) * QKV3 + h * DH + lq * 8;
    const unsigned short* kb = qkvb + (size_t)(b * NN) * QKV3 + INNER + h * DH + lq * 8;

    const short8 qf0 = *(const short8*)(qb + (size_t)(i0 + lrow) * QKV3);
    const short8 qf1 = *(const short8*)(qb + (size_t)(i0 + lrow) * QKV3 + 32);

    const unsigned short* krow = kb + (size_t)(jh * 256 + lrow) * QKV3;
    unsigned short* orow = attnb + (size_t)bh * PSTR + (size_t)(i0 + lrow) * NN +
                           jh * 256 + lq * 4;

    short8 ka[4], kc[4];
#pragma unroll
    for (int p = 0; p < 4; ++p) {
        const unsigned short* kp = krow + (size_t)p * 16 * QKV3;
        ka[p] = *(const short8*)(kp);
        kc[p] = *(const short8*)(kp + 32);
    }

    float lacc = 0.f;
#pragma unroll
    for (int jt = 0; jt < 16; ++jt) {
        const int s = jt & 3;
        short8 kf0 = ka[s], kf1 = kc[s];
        if (jt < 12) {
            const unsigned short* kp = krow + (size_t)(jt + 4) * 16 * QKV3;
            ka[s] = *(const short8*)(kp);
            kc[s] = *(const short8*)(kp + 32);
        }
        f32x4 acc = (f32x4){0.f, 0.f, 0.f, 0.f};
        acc = __builtin_amdgcn_mfma_f32_16x16x32_bf16(kf0, qf0, acc, 0, 0, 0);
        acc = __builtin_amdgcn_mfma_f32_16x16x32_bf16(kf1, qf1, acc, 0, 0, 0);
        float e0 = __expf(acc[0] * 0.125f);
        float e1 = __expf(acc[1] * 0.125f);
        float e2 = __expf(acc[2] * 0.125f);
        float e3 = __expf(acc[3] * 0.125f);
        lacc += (e0 + e1) + (e2 + e3);
        ushort4 o;
        o.x = f2bf(e0); o.y = f2bf(e1); o.z = f2bf(e2); o.w = f2bf(e3);
        *(ushort4*)(orow + jt * 16) = o;
    }
    lacc += __shfl_xor(lacc, 16, 64);
    lacc += __shfl_xor(lacc, 32, 64);
    if (lq == 0)
        lsum2[(size_t)jh * BB * HH * NN + (size_t)bh * NN + i0 + lrow] = lacc;
}

// ---------------------------------------------------------------------------
// Re-attention + LN over heads, bf16 in/out (fp32 math), 4 j per thread.
// Inputs are UNNORMALIZED exp values; scale by 1/(l0+l1) on load.
// attn planes at PADDED stride PSTR (de-aliases the 16-plane gather).
// ---------------------------------------------------------------------------
__global__ void reattn_ln_bf(unsigned short* __restrict__ attnb,
                             const float* __restrict__ lsum2,
                             const float* __restrict__ rw,
                             const float* __restrict__ gamma,
                             const float* __restrict__ beta) {
    __shared__ float w[16][16];
    __shared__ float gs[16], bs[16];
    const int tid = threadIdx.x;
    ((float*)w)[tid] = rw[tid];
    if (tid < 16) { gs[tid] = gamma[tid]; bs[tid] = beta[tid]; }
    __syncthreads();

    const size_t idx = (size_t)blockIdx.x * 256 + tid;  // over B*N*N/4
    const int j4 = (int)(idx & 127);
    const int i = (int)((idx >> 7) & 511);
    const int b = (int)(idx >> 16);
    unsigned short* base = attnb + (size_t)(b * HH) * PSTR + (size_t)i * NN + j4 * 4;
    const float* l0 = lsum2 + (size_t)(b * HH) * NN + i;
    const float* l1 = l0 + (size_t)BB * HH * NN;

    float v[16][4];
#pragma unroll
    for (int h = 0; h < 16; ++h) {
        const float linv = 1.0f / (l0[h * NN] + l1[h * NN]);
        ushort4 u = *(const ushort4*)(base + (size_t)h * PSTR);
        v[h][0] = bf2f(u.x) * linv; v[h][1] = bf2f(u.y) * linv;
        v[h][2] = bf2f(u.z) * linv; v[h][3] = bf2f(u.w) * linv;
    }
    float o[16][4];
    float me[4] = {0.f, 0.f, 0.f, 0.f};
#pragma unroll
    for (int g = 0; g < 16; ++g) {
        float s0 = 0.f, s1 = 0.f, s2 = 0.f, s3 = 0.f;
#pragma unroll
        for (int h = 0; h < 16; ++h) {
            const float wg = w[h][g];
            s0 += v[h][0] * wg; s1 += v[h][1] * wg;
            s2 += v[h][2] * wg; s3 += v[h][3] * wg;
        }
        o[g][0] = s0; o[g][1] = s1; o[g][2] = s2; o[g][3] = s3;
        me[0] += s0; me[1] += s1; me[2] += s2; me[3] += s3;
    }
#pragma unroll
    for (int r = 0; r < 4; ++r) me[r] *= 0.0625f;
    float va[4] = {0.f, 0.f, 0.f, 0.f};
#pragma unroll
    for (int g = 0; g < 16; ++g)
#pragma unroll
        for (int r = 0; r < 4; ++r) {
            float d = o[g][r] - me[r];
            va[r] += d * d;
        }
    float ri[4];
#pragma unroll
    for (int r = 0; r < 4; ++r) ri[r] = rsqrtf(va[r] * 0.0625f + 1e-3f);
#pragma unroll
    for (int g = 0; g < 16; ++g) {
        ushort4 u;
        u.x = f2bf((o[g][0] - me[0]) * ri[0] * gs[g] + bs[g]);
        u.y = f2bf((o[g][1] - me[1]) * ri[1] * gs[g] + bs[g]);
        u.z = f2bf((o[g][2] - me[2]) * ri[2] * gs[g] + bs[g]);
        u.w = f2bf((o[g][3] - me[3]) * ri[3] * gs[g] + bs[g]);
        *(ushort4*)(base + (size_t)g * PSTR) = u;
    }
}

// ---------------------------------------------------------------------------
// V transpose: qkvb [b,j,2048+h*64+d] -> vT [bh, d, j] (bf16)
// ---------------------------------------------------------------------------
__global__ void transpose_v(const unsigned short* __restrict__ qkvb,
                            unsigned short* __restrict__ vT) {
    __shared__ unsigned short t[32][33];
    const int bh = blockIdx.z;
    const int h = bh & 15, b = bh >> 4;
    const int j0 = blockIdx.x * 32, d0 = blockIdx.y * 32;
    const int tx = threadIdx.x & 31, ty = threadIdx.x >> 5;
    const unsigned short* src = qkvb + (size_t)(b * NN) * QKV3 + 2 * INNER + h * DH;
#pragma unroll
    for (int k = 0; k < 4; ++k)
        t[ty + 8 * k][tx] = src[(size_t)(j0 + ty + 8 * k) * QKV3 + d0 + tx];
    __syncthreads();
    unsigned short* dst = vT + (size_t)bh * DH * NN;
#pragma unroll
    for (int k = 0; k < 4; ++k)
        dst[(size_t)(d0 + ty + 8 * k) * NN + j0 + tx] = t[tx][ty + 8 * k];
}

// ---------------------------------------------------------------------------
// PV MFMA: outh[b,i,h*64+d] = sum_j P[bh,i,j] V[bh,j,d], P bf16 (padded
// plane stride), vT bf16. Transposed-D: lane holds col i, rows d.
// ---------------------------------------------------------------------------
__global__ __launch_bounds__(256) void pv_mfma(
    const unsigned short* __restrict__ attnb, const unsigned short* __restrict__ vT,
    unsigned short* __restrict__ outhb) {
    const int bh = blockIdx.y;
    const int h = bh & 15, b = bh >> 4;
    const int i0 = blockIdx.x * 128;
    __shared__ short Ps[128 * 64];
    __shared__ short Vs[64 * 64];
    const int tid = threadIdx.x;
    const int w = tid >> 6, l = tid & 63;
    const int lrow = l & 15, lq = l >> 4;
    const int lr8 = l >> 3;
    const int swd = ((l & 7) ^ (lr8 & 7)) * 8;

    f32x4 acc[2][4];
#pragma unroll
    for (int ic = 0; ic < 2; ++ic)
#pragma unroll
        for (int dt = 0; dt < 4; ++dt) acc[ic][dt] = (f32x4){0.f, 0.f, 0.f, 0.f};

    const unsigned short* pb = attnb + (size_t)bh * PSTR + (size_t)i0 * NN;
    const unsigned short* vb = vT + (size_t)bh * DH * NN;

    for (int j0 = 0; j0 < NN; j0 += 64) {
#pragma unroll
        for (int t = 0; t < 4; ++t) {
            int c = w * 4 + t;
            int r = c * 8 + lr8;
            __builtin_amdgcn_global_load_lds(
                (const AS1 void*)(pb + (size_t)r * NN + j0 + swd),
                (AS3 void*)(Ps + c * 512), 16, 0, 0);
        }
#pragma unroll
        for (int t = 0; t < 2; ++t) {
            int c = w * 2 + t;
            int d = c * 8 + lr8;
            __builtin_amdgcn_global_load_lds(
                (const AS1 void*)(vb + (size_t)d * NN + j0 + swd),
                (AS3 void*)(Vs + c * 512), 16, 0, 0);
        }
        __syncthreads();

#pragma unroll
        for (int kh = 0; kh < 2; ++kh) {
            short8 vf[4];
#pragma unroll
            for (int dt = 0; dt < 4; ++dt)
                vf[dt] = *(const short8*)(Vs + (dt * 16 + lrow) * 64 + (((kh * 4 + lq) ^ (lrow & 7)) * 8));
#pragma unroll
            for (int ic = 0; ic < 2; ++ic) {
                short8 pf = *(const short8*)(Ps + (w * 32 + ic * 16 + lrow) * 64 + (((kh * 4 + lq) ^ (lrow & 7)) * 8));
#pragma unroll
                for (int dt = 0; dt < 4; ++dt)
                    acc[ic][dt] = __builtin_amdgcn_mfma_f32_16x16x32_bf16(vf[dt], pf, acc[ic][dt], 0, 0, 0);
            }
        }
        __syncthreads();
    }

#pragma unroll
    for (int ic = 0; ic < 2; ++ic) {
        unsigned short* orow = outhb +
            ((size_t)(b * NN + i0 + w * 32 + ic * 16 + lrow)) * INNER + h * DH + lq * 4;
#pragma unroll
        for (int dt = 0; dt < 4; ++dt) {
            ushort4 o;
            o.x = f2bf(acc[ic][dt][0]); o.y = f2bf(acc[ic][dt][1]);
            o.z = f2bf(acc[ic][dt][2]); o.w = f2bf(acc[ic][dt][3]);
            *(ushort4*)(orow + dt * 16) = o;
        }
    }
}

// ---------------------------------------------------------------------------
extern "C" void kernel_launch(void* const* d_in, const int* in_sizes, int n_in,
                              void* d_out, int out_size, void* d_ws, size_t ws_size,
                              hipStream_t stream) {
    const float* x        = (const float*)d_in[0];
    const float* w_qkv    = (const float*)d_in[1];
    const float* reattn_w = (const float*)d_in[2];
    const float* ln_gamma = (const float*)d_in[3];
    const float* ln_beta  = (const float*)d_in[4];
    const float* w_out    = (const float*)d_in[5];
    const float* b_out    = (const float*)d_in[6];
    float* out = (float*)d_out;

    unsigned short* qkvb  = (unsigned short*)d_ws;                 // 12.58M
    unsigned short* attnb = qkvb + (size_t)BB * NN * QKV3;         // 128 * PSTR
    unsigned short* vTb   = attnb + (size_t)BB * HH * PSTR;        // 4.19M
    unsigned short* outhb = vTb + (size_t)BB * HH * DH * NN;       // 4.19M
    unsigned short* xb    = outhb + (size_t)BB * NN * INNER;       // 4.19M
    unsigned short* wqkvT = xb + (size_t)BB * NN * DD;             // 3.15M
    unsigned short* woutT = wqkvT + (size_t)DD * QKV3;             // 1.05M
    float*          lsum2 = (float*)(woutT + (size_t)INNER * INNER);  // 2*B*H*N f32

    dim3 blk(256);

    conv_bf16<<<dim3((BB * NN * DD) / 1024), blk, 0, stream>>>(x, xb);
    convT_bf16<<<dim3(QKV3 / 32, DD / 32), blk, 0, stream>>>(w_qkv, wqkvT, DD, QKV3);
    convT_bf16<<<dim3(INNER / 32, INNER / 32), blk, 0, stream>>>(w_out, woutT, INNER, INNER);

    // QKV projection -> bf16
    gemm_bf16_bf<<<dim3(QKV3 / 128, (BB * NN) / 128), blk, 0, stream>>>(
        xb, wqkvT, qkvb, BB * NN, QKV3, DD);

    // streaming scores: unnormalized exp -> attn bf16 (padded planes)
    scores_stream<<<dim3(NN / 64, 2, BB * HH), blk, 0, stream>>>(qkvb, attnb, lsum2);

    // re-attention + LN (normalizes by 1/(l0+l1) on load, in-place bf16)
    reattn_ln_bf<<<dim3((BB * NN * NN) / 1024), blk, 0, stream>>>(
        attnb, lsum2, reattn_w, ln_gamma, ln_beta);

    // V transpose -> [bh][d][j]
    transpose_v<<<dim3(NN / 32, DH / 32, BB * HH), blk, 0, stream>>>(qkvb, vTb);

    // P @ V -> outh bf16
    pv_mfma<<<dim3(NN / 128, BB * HH), blk, 0, stream>>>(attnb, vTb, outhb);

    // output projection + bias (fp32 out)
    gemm_bf16<<<dim3(INNER / 128, (BB * NN) / 128), blk, 0, stream>>>(
        outhb, woutT, out, b_out, BB * NN, INNER, INNER);
}